// Round 7
// baseline (351.498 us; speedup 1.0000x reference)
//
#include <hip/hip_runtime.h>
#include <math.h>

// Problem constants
#define Tn 30
#define Bn 16384
#define Hn 100
#define Pn 7

// Tiling: gates padded 100->128 units => N=512 (32 n-tiles); K padded 100->128 (4 kt of 32).
// 256 blocks x 1024 threads (16 waves). Wave (ag = w&7, rh = w>>3) owns unit-block ag
// (16 units, all 4 gates) for row-groups {2rh, 2rh+1}. B-frags (16/wave) in registers.
// h double-buffered in LDS in FRAG-MAJOR layout [rg][kt][lane][8] -> lane-contiguous
// ds_read_b128 (conflict-free). 1 barrier/step.
#define NFRAG 128                      // B-frags per matrix (32 nt x 4 kt)
#define FRAG_BYTES (NFRAG * 64 * 16)   // 131072 per matrix
#define WS_FRAG_OFF 4096
#define WS_W2_OFF (WS_FRAG_OFF + 3 * FRAG_BYTES)   // 28 W2 frags (7 ps x 4 kt)
#define RP 68                          // gin2 row pitch (ushorts)
#define HBF_USH 8192                   // one h buffer: 4 rg x 4 kt x 64 lanes x 8 ush
#define G2_USH (512 * RP)              // 34816
#define SMEM_BYTES ((2 * HBF_USH + G2_USH) * 2)    // 102400

typedef __attribute__((ext_vector_type(8))) short short8;   // 8 bf16 (4 VGPRs)
typedef __attribute__((ext_vector_type(4))) float floatx4;  // MFMA C/D

__device__ __forceinline__ float rcp_(float v) { return __builtin_amdgcn_rcpf(v); }
__device__ __forceinline__ float sig_(float v) { return rcp_(1.0f + __expf(-v)); }
__device__ __forceinline__ float tanh_(float v) { return 1.0f - 2.0f * rcp_(__expf(2.0f * v) + 1.0f); }
__device__ __forceinline__ unsigned f2bf(float v) {
    unsigned u = __float_as_uint(v);
    return (u + 0x7FFFu + ((u >> 16) & 1u)) >> 16;   // RNE
}

// A-frag read: buf[rg][kt][lane][8] -- 64 lanes x 16B contiguous (conflict-free b128)
__device__ __forceinline__ short8 ld_af(const unsigned short* buf, int rg, int kt, int lane) {
    return *(const short8*)(buf + ((rg * 4 + kt) * 64 + lane) * 8);
}

// Merged prep: gid<512 -> u1/wc1 rank-1 FC1 fold; else pack Whh1/Wih2/Whh2 + W2 B-frags.
// B[k][n]: n = lane&15, k = (lane>>4)*8 + jj  (16x16x32 bf16 B mapping, HW-verified R4-R6).
__global__ void prep_kernel(const float* __restrict__ W1, const float* __restrict__ b1,
                            const float* __restrict__ Wih1, const float* __restrict__ bih1,
                            const float* __restrict__ bhh1, const float* __restrict__ Whh1,
                            const float* __restrict__ Wih2, const float* __restrict__ Whh2,
                            const float* __restrict__ W2, float* __restrict__ ws) {
    int gid = blockIdx.x * 256 + threadIdx.x;   // 512 + 3*8192 + 1792 = 26880 total
    if (gid < 512) {
        int j = gid;
        if (j < 400) {
            float u = 0.f, w = 0.f;
            for (int k = 0; k < Hn; ++k) {
                float a = Wih1[j * Hn + k];
                u += a * W1[k];
                w += a * b1[k];
            }
            ws[j] = u;
            ws[400 + j] = w + bih1[j] + bhh1[j];
        }
        return;
    }
    int g = gid - 512;
    int lane = g & 63;
    int l = lane & 15, q = lane >> 4;
    unsigned short hh[8];
    uint4 u;
    if (g < 3 * NFRAG * 64) {
        int mat = g / (NFRAG * 64);
        int f = (g % (NFRAG * 64)) >> 6;
        int nt = f >> 2, kt = f & 3;
        int G = nt >> 3, ag = nt & 7;
        int j = ag * 16 + l;
        const float* W = (mat == 0) ? Whh1 : (mat == 1) ? Wih2 : Whh2;
        const float* wrow = W + (G * Hn + (j < Hn ? j : 0)) * Hn;
        int kbase = kt * 32 + q * 8;
#pragma unroll
        for (int jj = 0; jj < 8; ++jj) {
            int k = kbase + jj;
            hh[jj] = (j < Hn && k < Hn) ? (unsigned short)f2bf(wrow[k]) : (unsigned short)0;
        }
        u.x = (unsigned)hh[0] | ((unsigned)hh[1] << 16);
        u.y = (unsigned)hh[2] | ((unsigned)hh[3] << 16);
        u.z = (unsigned)hh[4] | ((unsigned)hh[5] << 16);
        u.w = (unsigned)hh[6] | ((unsigned)hh[7] << 16);
        ((uint4*)((char*)ws + WS_FRAG_OFF + mat * FRAG_BYTES))[f * 64 + lane] = u;
    } else {
        int t = g - 3 * NFRAG * 64;             // 0..1791
        int f = t >> 6;                         // ps*4 + kt
        int ps = f >> 2, kt = f & 3;
        int kbase = kt * 32 + q * 8;
#pragma unroll
        for (int jj = 0; jj < 8; ++jj) {
            int k = kbase + jj;
            hh[jj] = (l < Pn && k < Hn) ? (unsigned short)f2bf(W2[l * (Pn * Hn) + ps * Hn + k])
                                        : (unsigned short)0;
        }
        u.x = (unsigned)hh[0] | ((unsigned)hh[1] << 16);
        u.y = (unsigned)hh[2] | ((unsigned)hh[3] << 16);
        u.z = (unsigned)hh[4] | ((unsigned)hh[5] << 16);
        u.w = (unsigned)hh[6] | ((unsigned)hh[7] << 16);
        ((uint4*)((char*)ws + WS_W2_OFF))[f * 64 + lane] = u;
    }
}

__global__ __launch_bounds__(1024) void lstm_fused(
    const float* __restrict__ x,     // (T,B)
    const float* __restrict__ ws,    // u1/wc1 + packed frags
    const float* __restrict__ bih2,
    const float* __restrict__ bhh2,
    const float* __restrict__ b2,    // (7,)
    float* __restrict__ out)         // (B,7)
{
    extern __shared__ unsigned short sm[];
    unsigned short* hb0 = sm;                   // h double buffer, frag-major
    unsigned short* hb1 = sm + HBF_USH;
    unsigned short* g2 = sm + 2 * HBF_USH;      // gin2 bf16 [n 512][row RP]

    const int tid = threadIdx.x;
    const int wave = tid >> 6, lane = tid & 63;
    const int l = lane & 15, q = lane >> 4;
    const int ag = wave & 7, rh = wave >> 3;
    const int jcol = ag * 16 + l;               // unit column (0..127; <100 real)
    const int rowbase = blockIdx.x * 64;

    // h-write base for this lane (A-layout target of unit jcol):
    // ush addr = rg*2048 + (4q+r)*8 + wbase; even lane writes b32 covering units jcol,jcol+1
    const int wbase = (ag >> 1) * 512 + (((2 * ag + (l >> 3)) & 3) * 128) + (l & 7);

    // zero both h buffers (covers K-pad; pad units compute h=0 exactly each step)
    for (int i = tid; i < (2 * HBF_USH) / 2; i += 1024) ((unsigned*)sm)[i] = 0;

    // this wave's 16 Whh1 B-frags -> registers
    short8 bf[4][4];   // [G][kt]
    const short8* fr0 = (const short8*)((const char*)ws + WS_FRAG_OFF);
#pragma unroll
    for (int G = 0; G < 4; ++G)
#pragma unroll
        for (int kt = 0; kt < 4; ++kt)
            bf[G][kt] = fr0[((((G << 3) | ag) << 2) + kt) * 64 + lane];

    float u1v[4], wc1v[4];
#pragma unroll
    for (int G = 0; G < 4; ++G) {
        u1v[G] = (jcol < Hn) ? ws[G * Hn + jcol] : 0.f;
        wc1v[G] = (jcol < Hn) ? ws[400 + G * Hn + jcol] : 0.f;
    }
    floatx4 cst[2];   // cell state per rg2, rows 4q+r, unit jcol
    cst[0] = (floatx4){0.f, 0.f, 0.f, 0.f};
    cst[1] = (floatx4){0.f, 0.f, 0.f, 0.f};

    __syncthreads();   // h buffers zeroed

    // ---- Phase 1: LSTM1, 30 steps, 1 barrier/step ----
    for (int t = 0; t < Tn; ++t) {
        const unsigned short* hc = (t & 1) ? hb1 : hb0;
        unsigned short* hn = (t & 1) ? hb0 : hb1;
#pragma unroll
        for (int rg2 = 0; rg2 < 2; ++rg2) {
            const int rg = 2 * rh + rg2;
            float4 xv = *(const float4*)(x + t * Bn + rowbase + rg * 16 + 4 * q);
            floatx4 acc[4];
#pragma unroll
            for (int G = 0; G < 4; ++G)
#pragma unroll
                for (int r = 0; r < 4; ++r)
                    acc[G][r] = fmaf(xv[r], u1v[G], wc1v[G]);
#pragma unroll
            for (int kt = 0; kt < 4; ++kt) {
                short8 a = ld_af(hc, rg, kt, lane);
#pragma unroll
                for (int G = 0; G < 4; ++G)
                    acc[G] = __builtin_amdgcn_mfma_f32_16x16x32_bf16(a, bf[G][kt], acc[G], 0, 0, 0);
            }
#pragma unroll
            for (int r = 0; r < 4; ++r) {
                float iv = sig_(acc[0][r]);
                float fv = sig_(acc[1][r]);
                float gv = tanh_(acc[2][r]);
                float ov = sig_(acc[3][r]);
                float cc = fv * cst[rg2][r] + iv * gv;
                cst[rg2][r] = cc;
                unsigned us = f2bf(ov * tanh_(cc));
                unsigned pr = (unsigned)__shfl_xor((int)us, 1);
                unsigned pk = (l & 1) ? (pr | (us << 16)) : (us | (pr << 16));
                if (!(l & 1))
                    *(unsigned*)(hn + rg * 2048 + (4 * q + r) * 8 + wbase) = pk;
            }
        }
        __syncthreads();
    }
    // hb0 holds `last` (h after t=29).

    // ---- Wih2 frags; gin2 = bias2 + last·Wih2^T parked in LDS (bf16, wave-private cells) ----
    {
        const short8* fr = (const short8*)((const char*)ws + WS_FRAG_OFF + FRAG_BYTES);
#pragma unroll
        for (int G = 0; G < 4; ++G)
#pragma unroll
            for (int kt = 0; kt < 4; ++kt)
                bf[G][kt] = fr[((((G << 3) | ag) << 2) + kt) * 64 + lane];
    }
    {
        float bv[4];
#pragma unroll
        for (int G = 0; G < 4; ++G)
            bv[G] = (jcol < Hn) ? (bih2[G * Hn + jcol] + bhh2[G * Hn + jcol]) : 0.f;
#pragma unroll
        for (int rg2 = 0; rg2 < 2; ++rg2) {
            const int rg = 2 * rh + rg2;
            floatx4 acc[4];
#pragma unroll
            for (int G = 0; G < 4; ++G)
                acc[G] = (floatx4){bv[G], bv[G], bv[G], bv[G]};
#pragma unroll
            for (int kt = 0; kt < 4; ++kt) {
                short8 a = ld_af(hb0, rg, kt, lane);
#pragma unroll
                for (int G = 0; G < 4; ++G)
                    acc[G] = __builtin_amdgcn_mfma_f32_16x16x32_bf16(a, bf[G][kt], acc[G], 0, 0, 0);
            }
#pragma unroll
            for (int G = 0; G < 4; ++G) {
                int n = G * 128 + jcol;
                uint2 pk;
                pk.x = f2bf(acc[G][0]) | (f2bf(acc[G][1]) << 16);
                pk.y = f2bf(acc[G][2]) | (f2bf(acc[G][3]) << 16);
                *(uint2*)(g2 + n * RP + rg * 16 + 4 * q) = pk;
            }
        }
    }
    // ---- Whh2 frags ----
    {
        const short8* fr = (const short8*)((const char*)ws + WS_FRAG_OFF + 2 * FRAG_BYTES);
#pragma unroll
        for (int G = 0; G < 4; ++G)
#pragma unroll
            for (int kt = 0; kt < 4; ++kt)
                bf[G][kt] = fr[((((G << 3) | ag) << 2) + kt) * 64 + lane];
    }

    // ---- Phase 2: LSTM2, 7 steps; FC2 via MFMA on waves ag<2 (myrg = 2rh+ag) ----
    const short8* w2fr = (const short8*)((const char*)ws + WS_W2_OFF);
    floatx4 yfc = (floatx4){0.f, 0.f, 0.f, 0.f};
    const int myrg = 2 * rh + ag;

    for (int ps = 0; ps < Pn; ++ps) {
        int t = Tn + ps;
        const unsigned short* hc = (t & 1) ? hb1 : hb0;
        unsigned short* hn = (t & 1) ? hb0 : hb1;
#pragma unroll
        for (int rg2 = 0; rg2 < 2; ++rg2) {
            const int rg = 2 * rh + rg2;
            floatx4 acc[4];
#pragma unroll
            for (int G = 0; G < 4; ++G) {
                int n = G * 128 + jcol;
                uint2 pk = *(const uint2*)(g2 + n * RP + rg * 16 + 4 * q);
                acc[G][0] = __uint_as_float(pk.x << 16);
                acc[G][1] = __uint_as_float(pk.x & 0xFFFF0000u);
                acc[G][2] = __uint_as_float(pk.y << 16);
                acc[G][3] = __uint_as_float(pk.y & 0xFFFF0000u);
            }
#pragma unroll
            for (int kt = 0; kt < 4; ++kt) {
                short8 a = ld_af(hc, rg, kt, lane);
#pragma unroll
                for (int G = 0; G < 4; ++G)
                    acc[G] = __builtin_amdgcn_mfma_f32_16x16x32_bf16(a, bf[G][kt], acc[G], 0, 0, 0);
            }
#pragma unroll
            for (int r = 0; r < 4; ++r) {
                float iv = sig_(acc[0][r]);
                float fv = sig_(acc[1][r]);
                float gv = tanh_(acc[2][r]);
                float ov = sig_(acc[3][r]);
                float cc = fv * cst[rg2][r] + iv * gv;
                cst[rg2][r] = cc;
                unsigned us = f2bf(ov * tanh_(cc));
                unsigned pr = (unsigned)__shfl_xor((int)us, 1);
                unsigned pk = (l & 1) ? (pr | (us << 16)) : (us | (pr << 16));
                if (!(l & 1))
                    *(unsigned*)(hn + rg * 2048 + (4 * q + r) * 8 + wbase) = pk;
            }
        }
        // FC2: y[row][p] += h2^(ps) · W2-slice(ps-1); hc holds h2 of previous step (stable)
        if (ag < 2 && ps >= 1) {
#pragma unroll
            for (int kt = 0; kt < 4; ++kt) {
                short8 a = ld_af(hc, myrg, kt, lane);
                short8 wf = w2fr[((ps - 1) * 4 + kt) * 64 + lane];
                yfc = __builtin_amdgcn_mfma_f32_16x16x32_bf16(a, wf, yfc, 0, 0, 0);
            }
        }
        __syncthreads();
    }

    // ---- final FC2 (h2^(7) in hb1, slice 6), bias + sigmoid, store ----
    if (ag < 2) {
#pragma unroll
        for (int kt = 0; kt < 4; ++kt) {
            short8 a = ld_af(hb1, myrg, kt, lane);
            short8 wf = w2fr[(6 * 4 + kt) * 64 + lane];
            yfc = __builtin_amdgcn_mfma_f32_16x16x32_bf16(a, wf, yfc, 0, 0, 0);
        }
        if (l < Pn) {
            float bias = b2[l];
#pragma unroll
            for (int r = 0; r < 4; ++r)
                out[(rowbase + myrg * 16 + 4 * q + r) * Pn + l] = sig_(yfc[r] + bias);
        }
    }
}

extern "C" void kernel_launch(void* const* d_in, const int* in_sizes, int n_in,
                              void* d_out, int out_size, void* d_ws, size_t ws_size,
                              hipStream_t stream) {
    const float* x    = (const float*)d_in[0];
    const float* W1   = (const float*)d_in[1];
    const float* b1   = (const float*)d_in[2];
    const float* Wih1 = (const float*)d_in[3];
    const float* Whh1 = (const float*)d_in[4];
    const float* bih1 = (const float*)d_in[5];
    const float* bhh1 = (const float*)d_in[6];
    const float* Wih2 = (const float*)d_in[7];
    const float* Whh2 = (const float*)d_in[8];
    const float* bih2 = (const float*)d_in[9];
    const float* bhh2 = (const float*)d_in[10];
    const float* W2   = (const float*)d_in[11];
    const float* b2   = (const float*)d_in[12];
    float* out = (float*)d_out;
    float* ws  = (float*)d_ws;

    (void)hipFuncSetAttribute((const void*)lstm_fused,
                              hipFuncAttributeMaxDynamicSharedMemorySize, SMEM_BYTES);

    prep_kernel<<<(512 + 3 * NFRAG * 64 + 28 * 64) / 256, 256, 0, stream>>>(
        W1, b1, Wih1, bih1, bhh1, Whh1, Wih2, Whh2, W2, ws);
    lstm_fused<<<Bn / 64, 1024, SMEM_BYTES, stream>>>(x, ws, bih2, bhh2, b2, out);
}